// Round 6
// baseline (784.528 us; speedup 1.0000x reference)
//
#include <hip/hip_runtime.h>
#include <math.h>

#define NN    2048
#define BATCH 32
#define TILE  64
#define TPB   256
#define TPS   (NN / TILE)          // 32 tiles per side
#define NPOS  (TPS * TPS)          // 1024 tile positions
#define BGRP  8                    // batch-groups per tile position
#define BPG   (BATCH / BGRP)       // 4 batches per block
#define GRID_MAIN (NPOS * BGRP)    // 8192 blocks

// Path-A workspace need: one float per (batch, tile-position) = 128 KiB.
#define WS_NEED ((size_t)BATCH * NPOS * sizeof(float))

// out[b] = sigmoid(coef[0] + coef[1] + coef[2]*S1[b] + coef[3]*S2[b])
//   S1[b] = sum_ij Ms[1,0,i,j] * x[b,j,i]
//   S2[b] = sum_ij Ms[1,1,i,j] * x[b,j,i]^2
// (r=0 rows of Ms are never needed: trace^0 == 1.)
//
// No-LDS design: Ms is loop-invariant, so each block loads its 64x64 M
// fragments TRANSPOSED into registers once (scattered 16B-granule reads,
// L2/L3-served; 32 KB one-time per block). x then streams in natural row
// order: thread t reads float4 at (row j0 + (t>>4) + 16p, col i0 + 4*(t&15)),
// i.e. each wave = 4 rows x 256 B contiguous — full cache-line use, zero LDS,
// zero transpose barriers. 4 batches accumulate concurrently in registers
// (4 independent loads in flight per pass). One barrier per block (reduction).
template <int USE_WS>
__global__ __launch_bounds__(TPB) void trace_kernel(
    const float* __restrict__ x,     // (B, N, N)
    const float* __restrict__ Ms,    // (2, 2, N, N)
    const float* __restrict__ coef,  // (2, 2) flat [c00,c01,c10,c11]
    float* __restrict__ ws,          // Path A: [b*NPOS + pos]
    float* __restrict__ out)         // Path B: pre-zeroed accumulators
{
    __shared__ float wsum[TPB / 64][BPG];   // [wave][batch]

    const int t    = threadIdx.x;
    const int pos  = blockIdx.x >> 3;           // / BGRP
    const int grp  = blockIdx.x & (BGRP - 1);
    const int i0   = (pos / TPS) * TILE;
    const int j0   = (pos % TPS) * TILE;

    const int lane = t & 63;
    const int wave = t >> 6;
    const int il4  = (t & 15) * 4;   // i-offset within tile: 0,4,...,60
    const int jrb  = t >> 4;         // j-offset base: 0..15 (passes add 16)

    const float c2 = coef[2];
    const float c3 = coef[3];

    // ---- M^T fragments -> registers (once per block; L2/L3 absorbs the
    //      8x refetch across batch-groups; 32 MiB unique from HBM) ----
    const float* __restrict__ M10 = Ms + (size_t)2 * NN * NN;
    const float* __restrict__ M11 = Ms + (size_t)3 * NN * NN;
    float m10t[4][4], m11t[4][4];
#pragma unroll
    for (int p = 0; p < 4; ++p) {
        const int j = j0 + jrb + 16 * p;
#pragma unroll
        for (int c = 0; c < 4; ++c) {
            const size_t off = (size_t)(i0 + il4 + c) * NN + (size_t)j;
            m10t[p][c] = M10[off];
            m11t[p][c] = M11[off];
        }
    }

    // ---- stream x for 4 batches concurrently ----
    const float* __restrict__ xbase =
        x + ((size_t)grp * BPG) * NN * NN + (size_t)j0 * NN + (size_t)(i0 + il4);

    float s1[BPG], s2[BPG];
#pragma unroll
    for (int bb = 0; bb < BPG; ++bb) { s1[bb] = 0.f; s2[bb] = 0.f; }

#pragma unroll
    for (int p = 0; p < 4; ++p) {
        const size_t rowoff = (size_t)(jrb + 16 * p) * NN;
        float4 v[BPG];
#pragma unroll
        for (int bb = 0; bb < BPG; ++bb)
            v[bb] = *reinterpret_cast<const float4*>(
                xbase + (size_t)bb * NN * NN + rowoff);
#pragma unroll
        for (int bb = 0; bb < BPG; ++bb) {
            s1[bb] = fmaf(m10t[p][0], v[bb].x, s1[bb]);
            s1[bb] = fmaf(m10t[p][1], v[bb].y, s1[bb]);
            s1[bb] = fmaf(m10t[p][2], v[bb].z, s1[bb]);
            s1[bb] = fmaf(m10t[p][3], v[bb].w, s1[bb]);
            s2[bb] = fmaf(m11t[p][0], v[bb].x * v[bb].x, s2[bb]);
            s2[bb] = fmaf(m11t[p][1], v[bb].y * v[bb].y, s2[bb]);
            s2[bb] = fmaf(m11t[p][2], v[bb].z * v[bb].z, s2[bb]);
            s2[bb] = fmaf(m11t[p][3], v[bb].w * v[bb].w, s2[bb]);
        }
    }

    // ---- fold coef, reduce all 4 batch scalars, single barrier ----
    float z[BPG];
#pragma unroll
    for (int bb = 0; bb < BPG; ++bb) z[bb] = fmaf(c2, s1[bb], c3 * s2[bb]);
#pragma unroll
    for (int o = 32; o > 0; o >>= 1) {
#pragma unroll
        for (int bb = 0; bb < BPG; ++bb) z[bb] += __shfl_xor(z[bb], o, 64);
    }
    if (lane == 0) {
#pragma unroll
        for (int bb = 0; bb < BPG; ++bb) wsum[wave][bb] = z[bb];
    }
    __syncthreads();

    if (t < BPG) {
        const float zt = wsum[0][t] + wsum[1][t] + wsum[2][t] + wsum[3][t];
        const int b = grp * BPG + t;
        if (USE_WS) {
            ws[(size_t)b * NPOS + pos] = zt;
        } else {
            atomicAdd(&out[b], zt);
        }
    }
}

__global__ __launch_bounds__(TPB) void finalize_ws_kernel(
    const float* __restrict__ ws,
    const float* __restrict__ coef,
    float* __restrict__ out)
{
    __shared__ float wsum[TPB / 64];
    const int b = blockIdx.x;
    const int t = threadIdx.x;

    float s = 0.f;
#pragma unroll
    for (int m = 0; m < NPOS / TPB; ++m) s += ws[(size_t)b * NPOS + t + m * TPB];
#pragma unroll
    for (int o = 32; o > 0; o >>= 1) s += __shfl_xor(s, o, 64);
    if ((t & 63) == 0) wsum[t >> 6] = s;
    __syncthreads();
    if (t == 0) {
        const float z = coef[0] + coef[1] + wsum[0] + wsum[1] + wsum[2] + wsum[3];
        out[b] = 1.0f / (1.0f + expf(-z));
    }
}

__global__ void init_out_kernel(float* __restrict__ out)
{
    if (threadIdx.x < BATCH) out[threadIdx.x] = 0.f;
}

__global__ void finalize_atomic_kernel(const float* __restrict__ coef,
                                       float* __restrict__ out)
{
    const int b = threadIdx.x;
    if (b < BATCH) {
        const float z = coef[0] + coef[1] + out[b];
        out[b] = 1.0f / (1.0f + expf(-z));
    }
}

extern "C" void kernel_launch(void* const* d_in, const int* in_sizes, int n_in,
                              void* d_out, int out_size, void* d_ws, size_t ws_size,
                              hipStream_t stream) {
    const float* x    = (const float*)d_in[0];   // (32, 2048, 2048) f32
    const float* Ms   = (const float*)d_in[1];   // (2, 2, 2048, 2048) f32
    const float* coef = (const float*)d_in[2];   // (2, 2) f32
    float* out = (float*)d_out;                  // (32,) f32
    float* ws  = (float*)d_ws;

    if (ws_size >= WS_NEED) {
        // Path A: partials in (checked) workspace, no atomics.
        trace_kernel<1><<<GRID_MAIN, TPB, 0, stream>>>(x, Ms, coef, ws, out);
        finalize_ws_kernel<<<BATCH, TPB, 0, stream>>>(ws, coef, out);
    } else {
        // Path B: zero workspace — accumulate via atomics into out.
        init_out_kernel<<<1, 64, 0, stream>>>(out);
        trace_kernel<0><<<GRID_MAIN, TPB, 0, stream>>>(x, Ms, coef, ws, out);
        finalize_atomic_kernel<<<1, 64, 0, stream>>>(coef, out);
    }
}